// Round 7
// baseline (155.071 us; speedup 1.0000x reference)
//
#include <hip/hip_runtime.h>

// Smith-Waterman soft-DP, B=512, x: (512,151,151) f32, scalar output.
// One wave per batch; slots j = 64k+lane, k=0..2. Linear-domain DP
// (H = exp(h) * 2^-E). x delivered via a 32-slot diagonal-major LDS
// window refilled with aligned float4 row-chunks once per 8 diagonals.

#define CGO 6.737946999085467e-03f   // e^-5
#define CGE 3.678794411714423e-01f   // e^-1
#define L2E 1.4426950408889634f
#define LN2 0.6931471805599453f
#define RTHR 0x1p40f
#define RSC  0x1p-64f
#define NTOT 11674112                // 512*151*151

typedef float f4 __attribute__((ext_vector_type(4)));

#if __has_builtin(__builtin_amdgcn_exp2f)
#define EXP2(x) __builtin_amdgcn_exp2f(x)
#else
static __device__ __forceinline__ float EXP2_(float x){float r;asm("v_exp_f32 %0, %1":"=v"(r):"v"(x));return r;}
#define EXP2(x) EXP2_(x)
#endif

#if __has_builtin(__builtin_amdgcn_logf)
#define LOG2(x) __builtin_amdgcn_logf(x)
#else
static __device__ __forceinline__ float LOG2_(float x){float r;asm("v_log_f32 %0, %1":"=v"(r):"v"(x));return r;}
#define LOG2(x) LOG2_(x)
#endif

static __device__ __forceinline__ float rl(float v, int l){
    return __int_as_float(__builtin_amdgcn_readlane(__float_as_int(v), l));
}

#define DPP_UP 0x138   // wave_shr:1  (lane i <- i-1)
#define DPP_DN 0x130   // wave_shl:1  (lane i <- i+1)

template<int CTRL>
static __device__ __forceinline__ float dppz(float v){   // invalid lanes -> 0
    return __int_as_float(__builtin_amdgcn_update_dpp(
        0, __float_as_int(v), CTRL, 0xF, 0xF, true));
}
template<int CTRL>
static __device__ __forceinline__ float dppc(float old, float v){ // invalid -> old
    return __int_as_float(__builtin_amdgcn_update_dpp(
        __float_as_int(old), __float_as_int(v), CTRL, 0xF, 0xF, false));
}

// ---- refill: load 3 aligned float4 per row-group for superstep s ----
static __device__ __forceinline__
void loadL(const float* __restrict__ x, int bbase, int s, int lane,
           float (&L)[3][12]) {
    #pragma unroll
    for (int g = 0; g < 3; ++g) {
        const int r = 64*g + lane;
        if (r <= 150) {
            int m0 = (8*s + 19 - r) >> 2; if (m0 < 0) m0 = 0;
            int c4 = 4*m0; if (c4 > 144) c4 = 144;
            int gi = bbase + ((151*r + c4) & ~3);
            if (gi > NTOT - 12) gi = NTOT - 12;      // stays 16B-aligned
            const f4* p = (const f4*)(x + gi);
            const f4 a = p[0], b = p[1], c = p[2];
            L[g][0]=a[0]; L[g][1]=a[1]; L[g][2]=a[2];  L[g][3]=a[3];
            L[g][4]=b[0]; L[g][5]=b[1]; L[g][6]=b[2];  L[g][7]=b[3];
            L[g][8]=c[0]; L[g][9]=c[1]; L[g][10]=c[2]; L[g][11]=c[3];
        }
    }
}

// ---- commit loaded values into the LDS diagonal window (masked) ----
static __device__ __forceinline__
void writeL(float* lds, int bbase, int s, int lane, const float (&L)[3][12]) {
    const int dcap = 8*s + 26;
    #pragma unroll
    for (int g = 0; g < 3; ++g) {
        const int r = 64*g + lane;
        if (r <= 150) {
            int m0 = (8*s + 19 - r) >> 2; if (m0 < 0) m0 = 0;
            int c4 = 4*m0; if (c4 > 144) c4 = 144;
            int gi = bbase + ((151*r + c4) & ~3);
            if (gi > NTOT - 12) gi = NTOT - 12;
            const int cb = (gi - bbase) - 151*r;     // column of L[g][0]
            #pragma unroll
            for (int i = 0; i < 12; ++i) {
                const int c = cb + i;
                const int d = r + c;
                if (c >= c4 && c <= c4 + 7 && c <= 150 && d <= dcap)
                    lds[(d & 31)*160 + r] = L[g][i];
            }
        }
    }
}

static __device__ __forceinline__
float readCell(const float* lds, int t, int k, int lane) {
    const int halfT = (149 + t) >> 1;
    int r = halfT - 64*k - lane;
    r = r < 0 ? 0 : (r > 159 ? 159 : r);
    return lds[(t & 31)*160 + r];
}

// ---- one anti-diagonal step (SO = d&1, compile-time) ----
// Entry: EX0/EX1 = exp(cell) for diags d, d+1; RW0/RW1 = raw for d+2, d+3.
template<int SO>
static __device__ __forceinline__
void step(const int d, const int lane, const float* lds,
          float (&A)[3][3], float (&B)[3][3],
          float (&EX0)[3], float (&EX1)[3], float (&RW0)[3], float (&RW1)[3],
          const float oneE, float& S)
{
    const int half = (149 + d) >> 1;
    const int cvlo = half - (d < 149 ? d : 149);
    const int cvhi = half - (d > 149 ? d - 149 : 0);
    const bool cAct[3] = { cvlo <= 69, true, cvhi >= 122 };

    // LDS reads for diag d+4 (consumed 2 steps later)
    float rd[3];
    #pragma unroll
    for (int k = 0; k < 3; ++k) rd[k] = readCell(lds, d + 4, k, lane);

    // exp of raw(d+2): serves as x2(d) now, sx(d+2) later
    float e2[3];
    #pragma unroll
    for (int k = 0; k < 3; ++k) e2[k] = EXP2(RW0[k] * L2E);

    // neighbor gather from h1 (=B) via DPP
    float n0[3], n1[3], n2[3];
    if (SO) {   // odd: "right" uses h1[j-1], comps 0,1
        n0[0] = dppz<DPP_UP>(B[0][0]);
        n1[0] = dppz<DPP_UP>(B[0][1]);
        n0[1] = dppc<DPP_UP>(rl(B[0][0], 63), B[1][0]);
        n1[1] = dppc<DPP_UP>(rl(B[0][1], 63), B[1][1]);
        n0[2] = dppc<DPP_UP>(rl(B[1][0], 63), B[2][0]);
        n1[2] = dppc<DPP_UP>(rl(B[1][1], 63), B[2][1]);
        n2[0] = n2[1] = n2[2] = 0.0f;
    } else {    // even: "down" uses h1[j+1], comps 0,1,2
        n0[2] = dppz<DPP_DN>(B[2][0]);
        n1[2] = dppz<DPP_DN>(B[2][1]);
        n2[2] = dppz<DPP_DN>(B[2][2]);
        n0[1] = dppc<DPP_DN>(rl(B[2][0], 0), B[1][0]);
        n1[1] = dppc<DPP_DN>(rl(B[2][1], 0), B[1][1]);
        n2[1] = dppc<DPP_DN>(rl(B[2][2], 0), B[1][2]);
        n0[0] = dppc<DPP_DN>(rl(B[1][0], 0), B[0][0]);
        n1[0] = dppc<DPP_DN>(rl(B[1][1], 0), B[0][1]);
        n2[0] = dppc<DPP_DN>(rl(B[1][2], 0), B[0][2]);
    }

    #pragma unroll
    for (int k = 0; k < 3; ++k) {
        if (!cAct[k]) continue;
        const int lo = cvlo - 64*k, hi = cvhi - 64*k;
        const bool cv = (lane >= lo) && (lane <= hi);
        const float sxl = cv ? EX0[k] : 0.0f;
        const float x2l = cv ? e2[k]  : 0.0f;

        float h0 = sxl * (((A[k][0] + A[k][1]) + A[k][2]) + oneE);
        float h1, h2;
        if (SO) {
            h1 = fmaf(CGO, n0[k], CGE * n1[k]);
            h2 = fmaf(CGO, B[k][0] + B[k][1], CGE * B[k][2]);
        } else {
            h1 = fmaf(CGO, B[k][0], CGE * B[k][1]);
            h2 = fmaf(CGO, n0[k] + n1[k], CGE * n2[k]);
        }
        if (k == 2) {   // slots >= 150 don't exist
            const bool pad = lane >= 22;
            h0 = pad ? 0.0f : h0;
            h1 = pad ? 0.0f : h1;
            h2 = pad ? 0.0f : h2;
        }
        S = fmaf(x2l, (h0 + h1) + h2, S);
        A[k][0] = B[k][0]; A[k][1] = B[k][1]; A[k][2] = B[k][2];
        B[k][0] = h0;      B[k][1] = h1;      B[k][2] = h2;
    }

    // rotate FIFOs (renamed by full unroll within a superstep)
    #pragma unroll
    for (int k = 0; k < 3; ++k) {
        EX0[k] = EX1[k]; EX1[k] = e2[k];
        RW0[k] = RW1[k]; RW1[k] = rd[k];
    }
}

__global__ __launch_bounds__(64)
void sw_wave(const float* __restrict__ x, float* __restrict__ part,
             float* __restrict__ out_atomic, int use_atomic) {
    const int b = blockIdx.x;
    const int bbase = b * 22801;
    const int lane = threadIdx.x;

    __shared__ float lds[32 * 160];   // diag-major window: [(d&31)][row]

    float A[3][3], B[3][3];
    #pragma unroll
    for (int k = 0; k < 3; ++k)
        #pragma unroll
        for (int c = 0; c < 3; ++c) { A[k][c] = 0.0f; B[k][c] = 0.0f; }

    float L[3][12];
    // prologue: commit diags <= 18, then preload L(0); prime read FIFOs
    loadL(x, bbase, -2, lane, L); writeL(lds, bbase, -2, lane, L);
    loadL(x, bbase, -1, lane, L); writeL(lds, bbase, -1, lane, L);
    loadL(x, bbase, 0, lane, L);

    float EX0[3], EX1[3], RW0[3], RW1[3];
    #pragma unroll
    for (int k = 0; k < 3; ++k) {
        EX0[k] = EXP2(readCell(lds, 0, k, lane) * L2E);
        EX1[k] = EXP2(readCell(lds, 1, k, lane) * L2E);
        RW0[k] = readCell(lds, 2, k, lane);
        RW1[k] = readCell(lds, 3, k, lane);
    }

    float oneE = 1.0f;   // 2^-E
    float E = 0.0f;      // wave-uniform block-scale exponent
    float S = 0.0f;      // per-lane score sum, scaled by 2^-E

    for (int s = 0; s < 37; ++s) {
        if (s < 36) {
            writeL(lds, bbase, s, lane, L);   // commit window [8s+16, 8s+26]
            loadL(x, bbase, s + 1, lane, L);  // issue next superstep's loads
        }
        const int D = 8 * s;
        step<0>(D + 0, lane, lds, A, B, EX0, EX1, RW0, RW1, oneE, S);
        step<1>(D + 1, lane, lds, A, B, EX0, EX1, RW0, RW1, oneE, S);
        step<0>(D + 2, lane, lds, A, B, EX0, EX1, RW0, RW1, oneE, S);
        step<1>(D + 3, lane, lds, A, B, EX0, EX1, RW0, RW1, oneE, S);
        step<0>(D + 4, lane, lds, A, B, EX0, EX1, RW0, RW1, oneE, S);
        step<1>(D + 5, lane, lds, A, B, EX0, EX1, RW0, RW1, oneE, S);
        step<0>(D + 6, lane, lds, A, B, EX0, EX1, RW0, RW1, oneE, S);
        step<1>(D + 7, lane, lds, A, B, EX0, EX1, RW0, RW1, oneE, S);

        // renorm (wave-uniform; ~every few supersteps on this data)
        float m = B[0][0];
        m = fmaxf(m, B[0][1]); m = fmaxf(m, B[0][2]);
        m = fmaxf(m, B[1][0]); m = fmaxf(m, B[1][1]); m = fmaxf(m, B[1][2]);
        m = fmaxf(m, B[2][0]); m = fmaxf(m, B[2][1]); m = fmaxf(m, B[2][2]);
        if (__any(m > RTHR)) {
            #pragma unroll
            for (int k = 0; k < 3; ++k)
                #pragma unroll
                for (int c = 0; c < 3; ++c) { A[k][c] *= RSC; B[k][c] *= RSC; }
            S *= RSC; oneE *= RSC; E += 64.0f;
        }
    }
    // tail: diags 296..298
    step<0>(296, lane, lds, A, B, EX0, EX1, RW0, RW1, oneE, S);
    step<1>(297, lane, lds, A, B, EX0, EX1, RW0, RW1, oneE, S);
    step<0>(298, lane, lds, A, B, EX0, EX1, RW0, RW1, oneE, S);

    // wave sum of S (E uniform across lanes)
    #pragma unroll
    for (int off = 32; off; off >>= 1) S += __shfl_xor(S, off, 64);
    if (lane == 0) {
        const float val = LN2 * (E + LOG2(S));
        if (use_atomic) atomicAdd(out_atomic, val);
        else            part[b] = val;
    }
}

__global__ __launch_bounds__(256)
void final_reduce(const float* __restrict__ part, float* __restrict__ out) {
    const int t = threadIdx.x;
    float v = part[t] + part[t + 256];
    #pragma unroll
    for (int off = 32; off; off >>= 1) v += __shfl_xor(v, off);
    __shared__ float ws[4];
    if ((t & 63) == 0) ws[t >> 6] = v;
    __syncthreads();
    if (t == 0) out[0] = ws[0] + ws[1] + ws[2] + ws[3];
}

extern "C" void kernel_launch(void* const* d_in, const int* in_sizes, int n_in,
                              void* d_out, int out_size, void* d_ws, size_t ws_size,
                              hipStream_t stream) {
    const float* x = (const float*)d_in[0];
    float* out = (float*)d_out;

    if (ws_size >= 512 * sizeof(float)) {
        float* part = (float*)d_ws;
        sw_wave<<<512, 64, 0, stream>>>(x, part, nullptr, 0);
        final_reduce<<<1, 256, 0, stream>>>(part, out);
    } else {
        hipMemsetAsync(out, 0, sizeof(float), stream);
        sw_wave<<<512, 64, 0, stream>>>(x, nullptr, out, 1);
    }
}

// Round 8
// 122.148 us; speedup vs baseline: 1.2695x; 1.2695x over previous
//
#include <hip/hip_runtime.h>

// Smith-Waterman soft-DP, B=512, x: (512,151,151) f32, scalar output.
// Two-phase: (1) prep kernel transposes x into diagonal-major f16 exp-domain
// layout xd[b][t][j] (192-wide rows, 308 diags) in d_ws; (2) one wave per
// batch runs the linear-domain DP with 3 coalesced f16 loads per diagonal,
// a period-4 register FIFO (statically unrolled, zero movs), DPP neighbors.

#define CGO 6.737946999085467e-03f   // e^-5
#define CGE 3.678794411714423e-01f   // e^-1
#define L2E 1.4426950408889634f
#define LN2 0.6931471805599453f
#define RTHR 0x1p60f
#define RSC  0x1p-64f
#define NTOT 11674112                // 512*151*151

#define DW    192                    // xd row width (slots)
#define DROWS 308                    // xd rows (diagonals)
#define PB    (DW * DROWS)           // halfs per batch

#if __has_builtin(__builtin_amdgcn_exp2f)
#define EXP2(x) __builtin_amdgcn_exp2f(x)
#else
static __device__ __forceinline__ float EXP2_(float x){float r;asm("v_exp_f32 %0, %1":"=v"(r):"v"(x));return r;}
#define EXP2(x) EXP2_(x)
#endif

#if __has_builtin(__builtin_amdgcn_logf)
#define LOG2(x) __builtin_amdgcn_logf(x)
#else
static __device__ __forceinline__ float LOG2_(float x){float r;asm("v_log_f32 %0, %1":"=v"(r):"v"(x));return r;}
#define LOG2(x) LOG2_(x)
#endif

static __device__ __forceinline__ float rl(float v, int l){
    return __int_as_float(__builtin_amdgcn_readlane(__float_as_int(v), l));
}

#define DPP_UP 0x138   // wave_shr:1  (lane i <- i-1)
#define DPP_DN 0x130   // wave_shl:1  (lane i <- i+1)

template<int CTRL>
static __device__ __forceinline__ float dppz(float v){   // invalid lanes -> 0
    return __int_as_float(__builtin_amdgcn_update_dpp(
        0, __float_as_int(v), CTRL, 0xF, 0xF, true));
}
template<int CTRL>
static __device__ __forceinline__ float dppc(float old, float v){ // invalid -> old
    return __int_as_float(__builtin_amdgcn_update_dpp(
        __float_as_int(old), __float_as_int(v), CTRL, 0xF, 0xF, false));
}

// ================= phase 1: transpose + exp into diag-major f16 =============
__global__ __launch_bounds__(256)
void prep_kernel(const float* __restrict__ x, _Float16* __restrict__ xd) {
    const int b  = blockIdx.x / 77;
    const int tg = blockIdx.x % 77;
    const int t  = tg * 4 + (threadIdx.x >> 6);      // 0..307
    const int lane = threadIdx.x & 63;
    const float* xb = x + (size_t)b * 22801;
    _Float16* row = xd + (size_t)b * PB + t * DW;
    const int halfT = (149 + t) >> 1;
    #pragma unroll
    for (int m = 0; m < 3; ++m) {
        const int j = 64 * m + lane;
        const int r = halfT - j;
        const int c = t - r;
        float e = 0.0f;
        if (((unsigned)r <= 150u) & ((unsigned)c <= 150u))
            e = EXP2(xb[151 * r + c] * L2E);
        row[j] = (_Float16)e;
    }
}

// ================= phase 2: DP, one wave per batch ==========================
// Step d: h1 read from H1, h2 read from H2, new h written into H2 (role swap
// per step). Vs = exp-value of diag d (sx), Vx = diag d+2 (x2); commit slot
// Vs <- cvt(Rc) (= diag d+4, loaded 4 steps ago); Rc <- load(diag d+8).
template<int SO>
static __device__ __forceinline__
void stepF(const int d, const int lane, const _Float16* __restrict__ xdb,
           float (&H1)[3][3], float (&H2)[3][3],
           float (&Vs)[3], float (&Vx)[3], _Float16 (&Rc)[3],
           const float oneE, float& S)
{
    const int half = (149 + d) >> 1;
    const int cvlo = half - (d < 149 ? d : 149);
    const int cvhi = half - (d > 149 ? d - 149 : 0);
    const bool cAct[3] = { cvlo <= 69, true, cvhi >= 122 };

    // issue coalesced prefetch for diag d+8 (128B per load, 2 lines)
    const _Float16* p = xdb + (d + 8) * DW + lane;
    const _Float16 l0 = p[0], l1 = p[64], l2 = p[128];

    // neighbor gather from H1 via DPP
    float n0[3], n1[3], n2[3];
    if (SO) {   // odd: "right" uses h1[j-1], comps 0,1
        n0[0] = dppz<DPP_UP>(H1[0][0]);
        n1[0] = dppz<DPP_UP>(H1[0][1]);
        n0[1] = dppc<DPP_UP>(rl(H1[0][0], 63), H1[1][0]);
        n1[1] = dppc<DPP_UP>(rl(H1[0][1], 63), H1[1][1]);
        n0[2] = dppc<DPP_UP>(rl(H1[1][0], 63), H1[2][0]);
        n1[2] = dppc<DPP_UP>(rl(H1[1][1], 63), H1[2][1]);
        n2[0] = n2[1] = n2[2] = 0.0f;
    } else {    // even: "down" uses h1[j+1], comps 0,1,2
        n0[2] = dppz<DPP_DN>(H1[2][0]);
        n1[2] = dppz<DPP_DN>(H1[2][1]);
        n2[2] = dppz<DPP_DN>(H1[2][2]);
        n0[1] = dppc<DPP_DN>(rl(H1[2][0], 0), H1[1][0]);
        n1[1] = dppc<DPP_DN>(rl(H1[2][1], 0), H1[1][1]);
        n2[1] = dppc<DPP_DN>(rl(H1[2][2], 0), H1[1][2]);
        n0[0] = dppc<DPP_DN>(rl(H1[1][0], 0), H1[0][0]);
        n1[0] = dppc<DPP_DN>(rl(H1[1][1], 0), H1[0][1]);
        n2[0] = dppc<DPP_DN>(rl(H1[1][2], 0), H1[0][2]);
    }

    #pragma unroll
    for (int k = 0; k < 3; ++k) {
        if (!cAct[k]) continue;
        const int lo = cvlo - 64 * k, hi = cvhi - 64 * k;
        const bool cv = (lane >= lo) && (lane <= hi);
        const float sxl = cv ? Vs[k] : 0.0f;
        const float x2l = cv ? Vx[k] : 0.0f;

        float h0 = sxl * (((H2[k][0] + H2[k][1]) + H2[k][2]) + oneE);
        float h1, h2;
        if (SO) {
            h1 = fmaf(CGO, n0[k], CGE * n1[k]);
            h2 = fmaf(CGO, H1[k][0] + H1[k][1], CGE * H1[k][2]);
        } else {
            h1 = fmaf(CGO, H1[k][0], CGE * H1[k][1]);
            h2 = fmaf(CGO, n0[k] + n1[k], CGE * n2[k]);
        }
        if (k == 2) {   // slots >= 150 don't exist
            const bool pad = lane >= 22;
            h0 = pad ? 0.0f : h0;
            h1 = pad ? 0.0f : h1;
            h2 = pad ? 0.0f : h2;
        }
        S = fmaf(x2l, (h0 + h1) + h2, S);
        H2[k][0] = h0; H2[k][1] = h1; H2[k][2] = h2;
    }

    // FIFO: commit diag d+4 (raw loaded 4 steps ago), insert new raw (d+8)
    Vs[0] = (float)Rc[0]; Vs[1] = (float)Rc[1]; Vs[2] = (float)Rc[2];
    Rc[0] = l0; Rc[1] = l1; Rc[2] = l2;
}

__global__ __launch_bounds__(64)
void sw_fast(const _Float16* __restrict__ xd, float* __restrict__ part) {
    const int b = blockIdx.x;
    const _Float16* xdb = xd + (size_t)b * PB;
    const int lane = threadIdx.x;

    float Ha[3][3], Hb[3][3];
    #pragma unroll
    for (int k = 0; k < 3; ++k)
        #pragma unroll
        for (int c = 0; c < 3; ++c) { Ha[k][c] = 0.0f; Hb[k][c] = 0.0f; }

    // prime FIFO: V[q] = diag q (f32), R[q] = raw diag 4+q (f16)
    float V0[3], V1[3], V2[3], V3[3];
    _Float16 R0[3], R1[3], R2[3], R3[3];
    #pragma unroll
    for (int k = 0; k < 3; ++k) {
        V0[k] = (float)xdb[0 * DW + 64 * k + lane];
        V1[k] = (float)xdb[1 * DW + 64 * k + lane];
        V2[k] = (float)xdb[2 * DW + 64 * k + lane];
        V3[k] = (float)xdb[3 * DW + 64 * k + lane];
        R0[k] = xdb[4 * DW + 64 * k + lane];
        R1[k] = xdb[5 * DW + 64 * k + lane];
        R2[k] = xdb[6 * DW + 64 * k + lane];
        R3[k] = xdb[7 * DW + 64 * k + lane];
    }

    float oneE = 1.0f;   // 2^-E
    float E = 0.0f;      // wave-uniform block-scale exponent
    float S = 0.0f;      // per-lane score sum, scaled by 2^-E

    #define RENORM() do {                                                    \
        float m_ = Hb[0][0];                                                 \
        m_ = fmaxf(m_, Hb[0][1]); m_ = fmaxf(m_, Hb[0][2]);                  \
        m_ = fmaxf(m_, Hb[1][0]); m_ = fmaxf(m_, Hb[1][1]);                  \
        m_ = fmaxf(m_, Hb[1][2]); m_ = fmaxf(m_, Hb[2][0]);                  \
        m_ = fmaxf(m_, Hb[2][1]); m_ = fmaxf(m_, Hb[2][2]);                  \
        if (__any(m_ > RTHR)) {                                              \
            _Pragma("unroll")                                                \
            for (int k_ = 0; k_ < 3; ++k_)                                   \
                _Pragma("unroll")                                            \
                for (int c_ = 0; c_ < 3; ++c_) {                             \
                    Ha[k_][c_] *= RSC; Hb[k_][c_] *= RSC;                    \
                }                                                            \
            S *= RSC; oneE *= RSC; E += 64.0f;                               \
        }                                                                    \
    } while (0)

    for (int d = 0; d < 296; d += 4) {
        stepF<0>(d + 0, lane, xdb, Hb, Ha, V0, V2, R0, oneE, S);
        stepF<1>(d + 1, lane, xdb, Ha, Hb, V1, V3, R1, oneE, S);
        RENORM();
        stepF<0>(d + 2, lane, xdb, Hb, Ha, V2, V0, R2, oneE, S);
        stepF<1>(d + 3, lane, xdb, Ha, Hb, V3, V1, R3, oneE, S);
        RENORM();
    }
    stepF<0>(296, lane, xdb, Hb, Ha, V0, V2, R0, oneE, S);
    stepF<1>(297, lane, xdb, Ha, Hb, V1, V3, R1, oneE, S);
    stepF<0>(298, lane, xdb, Hb, Ha, V2, V0, R2, oneE, S);

    // wave sum of S (E uniform across lanes)
    #pragma unroll
    for (int off = 32; off; off >>= 1) S += __shfl_xor(S, off, 64);
    if (lane == 0) part[b] = LN2 * (E + LOG2(S));
}

// ================= fallback (validated round-5 kernel) ======================
template<int SO>
static __device__ __forceinline__
void stepFB(const int d, const float* __restrict__ xb, const int lane, const int j150,
            float (&B)[3][3], float (&A)[3][3], float (&Q)[3][3], float (&R)[4][3],
            const float oneE, float& S)
{
    const int half  = (149 + d) >> 1;
    const int cvlo  = half - (d < 149 ? d : 149);
    const int cvhi  = half - (d > 149 ? d - 149 : 0);
    const bool cAct[3] = { cvlo <= 69, true, cvhi >= 122 };
    const int t     = d + 7;
    const int halfL = (149 + t) >> 1;
    const int jloF  = halfL - (t < 150 ? t : 150);
    const int jhiF  = halfL - (t > 150 ? t - 150 : 0);
    const bool dol  = t <= 300;
    const bool lAct[3] = { dol && (jloF <= 63),
                           dol && (jhiF >= 64) && (jloF <= 127),
                           dol && (jhiF >= 128) };
    const int selS  = 150 * halfL + t;

    float ld[3] = {0.0f, 0.0f, 0.0f};
    #pragma unroll
    for (int k = 0; k < 3; ++k) {
        if (lAct[k]) {
            int idx = selS - j150 - 9600 * k;
            idx = idx < 0 ? 0 : idx;
            idx = idx > 22800 ? 22800 : idx;
            ld[k] = xb[idx];
        }
    }

    float n0[3], n1[3], n2[3];
    if (SO) {
        n0[0] = dppz<DPP_UP>(B[0][0]);
        n1[0] = dppz<DPP_UP>(B[0][1]);
        n0[1] = dppc<DPP_UP>(rl(B[0][0], 63), B[1][0]);
        n1[1] = dppc<DPP_UP>(rl(B[0][1], 63), B[1][1]);
        n0[2] = dppc<DPP_UP>(rl(B[1][0], 63), B[2][0]);
        n1[2] = dppc<DPP_UP>(rl(B[1][1], 63), B[2][1]);
        n2[0] = n2[1] = n2[2] = 0.0f;
    } else {
        n0[2] = dppz<DPP_DN>(B[2][0]);
        n1[2] = dppz<DPP_DN>(B[2][1]);
        n2[2] = dppz<DPP_DN>(B[2][2]);
        n0[1] = dppc<DPP_DN>(rl(B[2][0], 0), B[1][0]);
        n1[1] = dppc<DPP_DN>(rl(B[2][1], 0), B[1][1]);
        n2[1] = dppc<DPP_DN>(rl(B[2][2], 0), B[1][2]);
        n0[0] = dppc<DPP_DN>(rl(B[1][0], 0), B[0][0]);
        n1[0] = dppc<DPP_DN>(rl(B[1][1], 0), B[0][1]);
        n2[0] = dppc<DPP_DN>(rl(B[1][2], 0), B[0][2]);
    }

    #pragma unroll
    for (int k = 0; k < 3; ++k) {
        if (!cAct[k]) continue;
        const int lo = cvlo - 64 * k, hi = cvhi - 64 * k;
        const bool cv = (lane >= lo) && (lane <= hi);
        const float sxl = cv ? Q[0][k] : 0.0f;
        const float x2l = cv ? Q[2][k] : 0.0f;

        float h0 = sxl * (((A[k][0] + A[k][1]) + A[k][2]) + oneE);
        float h1, h2;
        if (SO) {
            h1 = fmaf(CGO, n0[k], CGE * n1[k]);
            h2 = fmaf(CGO, B[k][0] + B[k][1], CGE * B[k][2]);
        } else {
            h1 = fmaf(CGO, B[k][0], CGE * B[k][1]);
            h2 = fmaf(CGO, n0[k] + n1[k], CGE * n2[k]);
        }
        if (k == 2) {
            const bool pad = lane >= 22;
            h0 = pad ? 0.0f : h0;
            h1 = pad ? 0.0f : h1;
            h2 = pad ? 0.0f : h2;
        }
        S = fmaf(x2l, (h0 + h1) + h2, S);
        A[k][0] = B[k][0]; A[k][1] = B[k][1]; A[k][2] = B[k][2];
        B[k][0] = h0;      B[k][1] = h1;      B[k][2] = h2;
    }

    #pragma unroll
    for (int k = 0; k < 3; ++k) {
        Q[0][k] = Q[1][k]; Q[1][k] = Q[2][k];
        Q[2][k] = EXP2(R[0][k] * L2E);
        R[0][k] = R[1][k]; R[1][k] = R[2][k]; R[2][k] = R[3][k];
        R[3][k] = ld[k];
    }
}

__global__ __launch_bounds__(64)
void sw_wave_fb(const float* __restrict__ x, float* __restrict__ part,
                float* __restrict__ out_atomic, int use_atomic) {
    const int b = blockIdx.x;
    const float* xb = x + (size_t)b * 22801;
    const int lane = threadIdx.x;
    const int j150 = 150 * lane;

    float B[3][3], A[3][3], Q[3][3], R[4][3];
    #pragma unroll
    for (int k = 0; k < 3; ++k)
        #pragma unroll
        for (int c = 0; c < 3; ++c) { B[k][c] = 0.0f; A[k][c] = 0.0f; }
    #pragma unroll
    for (int i = 0; i < 3; ++i) { Q[i][0] = 0.0f; Q[i][2] = 0.0f; }
    #pragma unroll
    for (int i = 0; i < 4; ++i) { R[i][0] = 0.0f; R[i][2] = 0.0f; }

    #pragma unroll
    for (int t = 0; t < 3; ++t) {
        const int halfL = (149 + t) >> 1;
        int idx = 150 * halfL + t - j150 - 9600;
        idx = idx < 0 ? 0 : idx; idx = idx > 22800 ? 22800 : idx;
        Q[t][1] = EXP2(xb[idx] * L2E);
    }
    #pragma unroll
    for (int t = 3; t < 7; ++t) {
        const int halfL = (149 + t) >> 1;
        int idx = 150 * halfL + t - j150 - 9600;
        idx = idx < 0 ? 0 : idx; idx = idx > 22800 ? 22800 : idx;
        R[t - 3][1] = xb[idx];
    }

    float oneE = 1.0f, E = 0.0f, S = 0.0f;

    for (int d = 0; d < 298; d += 2) {
        stepFB<0>(d,     xb, lane, j150, B, A, Q, R, oneE, S);
        stepFB<1>(d + 1, xb, lane, j150, B, A, Q, R, oneE, S);
        float m = B[0][0];
        m = fmaxf(m, B[0][1]); m = fmaxf(m, B[0][2]);
        m = fmaxf(m, B[1][0]); m = fmaxf(m, B[1][1]); m = fmaxf(m, B[1][2]);
        m = fmaxf(m, B[2][0]); m = fmaxf(m, B[2][1]); m = fmaxf(m, B[2][2]);
        if (__any(m > RTHR)) {
            #pragma unroll
            for (int k = 0; k < 3; ++k)
                #pragma unroll
                for (int c = 0; c < 3; ++c) { A[k][c] *= RSC; B[k][c] *= RSC; }
            S *= RSC; oneE *= RSC; E += 64.0f;
        }
    }
    stepFB<0>(298, xb, lane, j150, B, A, Q, R, oneE, S);

    #pragma unroll
    for (int off = 32; off; off >>= 1) S += __shfl_xor(S, off, 64);
    if (lane == 0) {
        const float val = LN2 * (E + LOG2(S));
        if (use_atomic) atomicAdd(out_atomic, val);
        else            part[b] = val;
    }
}

// ================= final reduce =============================================
__global__ __launch_bounds__(256)
void final_reduce(const float* __restrict__ part, float* __restrict__ out) {
    const int t = threadIdx.x;
    float v = part[t] + part[t + 256];
    #pragma unroll
    for (int off = 32; off; off >>= 1) v += __shfl_xor(v, off);
    __shared__ float ws[4];
    if ((t & 63) == 0) ws[t >> 6] = v;
    __syncthreads();
    if (t == 0) out[0] = ws[0] + ws[1] + ws[2] + ws[3];
}

extern "C" void kernel_launch(void* const* d_in, const int* in_sizes, int n_in,
                              void* d_out, int out_size, void* d_ws, size_t ws_size,
                              hipStream_t stream) {
    const float* x = (const float*)d_in[0];
    float* out = (float*)d_out;

    const size_t need = 4096 + (size_t)512 * PB * sizeof(_Float16);
    if (ws_size >= need) {
        float* part = (float*)d_ws;                       // 2KB
        _Float16* xd = (_Float16*)((char*)d_ws + 4096);
        prep_kernel<<<512 * 77, 256, 0, stream>>>(x, xd);
        sw_fast<<<512, 64, 0, stream>>>(xd, part);
        final_reduce<<<1, 256, 0, stream>>>(part, out);
    } else if (ws_size >= 2048) {
        float* part = (float*)d_ws;
        sw_wave_fb<<<512, 64, 0, stream>>>(x, part, nullptr, 0);
        final_reduce<<<1, 256, 0, stream>>>(part, out);
    } else {
        hipMemsetAsync(out, 0, sizeof(float), stream);
        sw_wave_fb<<<512, 64, 0, stream>>>(x, nullptr, out, 1);
    }
}

// Round 9
// 88.447 us; speedup vs baseline: 1.7533x; 1.3810x over previous
//
#include <hip/hip_runtime.h>

// Smith-Waterman soft-DP, B=512, x: (512,151,151) f32, scalar output.
// Single fused kernel, one wave per batch.
// Phase A: coalesced read of x[b], exp2, stored row-major f16 in LDS (45.6KB).
// Phase B: linear-domain DP (H = exp(h) * 2^-E); 3 ds_read_u16 per diagonal
// (bank-conflict-free by stride), 4-step register FIFO (static, zero movs),
// DPP neighbor exchange, fully branchless 4-step bodies (renorm via selects,
// k2 block compiled out for d<92).

#define CGO 6.737946999085467e-03f   // e^-5
#define CGE 3.678794411714423e-01f   // e^-1
#define L2E 1.4426950408889634f
#define LN2 0.6931471805599453f
#define RTHR 0x1p60f
#define RSC  0x1p-64f

#if __has_builtin(__builtin_amdgcn_exp2f)
#define EXP2(x) __builtin_amdgcn_exp2f(x)
#else
static __device__ __forceinline__ float EXP2_(float x){float r;asm("v_exp_f32 %0, %1":"=v"(r):"v"(x));return r;}
#define EXP2(x) EXP2_(x)
#endif

#if __has_builtin(__builtin_amdgcn_logf)
#define LOG2(x) __builtin_amdgcn_logf(x)
#else
static __device__ __forceinline__ float LOG2_(float x){float r;asm("v_log_f32 %0, %1":"=v"(r):"v"(x));return r;}
#define LOG2(x) LOG2_(x)
#endif

static __device__ __forceinline__ float rl(float v, int l){
    return __int_as_float(__builtin_amdgcn_readlane(__float_as_int(v), l));
}

#define DPP_UP 0x138   // wave_shr:1  (lane i <- i-1)
#define DPP_DN 0x130   // wave_shl:1  (lane i <- i+1)

template<int CTRL>
static __device__ __forceinline__ float dppz(float v){   // invalid lanes -> 0
    return __int_as_float(__builtin_amdgcn_update_dpp(
        0, __float_as_int(v), CTRL, 0xF, 0xF, true));
}
template<int CTRL>
static __device__ __forceinline__ float dppc(float old, float v){ // invalid -> old
    return __int_as_float(__builtin_amdgcn_update_dpp(
        __float_as_int(old), __float_as_int(v), CTRL, 0xF, 0xF, false));
}

// row-major LDS index of diag-t, slot-j cell: idx = 150*halfT - 150*j + t
static __device__ __forceinline__ int cellIdx(int t, int j150k){
    const int halfT = (149 + t) >> 1;
    int idx = 150 * halfT + t - j150k;
    idx = idx < 0 ? 0 : idx;
    idx = idx > 22800 ? 22800 : idx;
    return idx;
}

// ---- one anti-diagonal step (SO = d&1; K2 = compute k=2 block) ----
// Entry: Vs = exp(cell) diag d, Vx = diag d+2, Rc = raw f16 diag d+4.
// Issues LDS reads for diag d+8; commits Vs <- cvt(Rc), Rc <- new.
template<int SO, bool K2>
static __device__ __forceinline__
void stepF(const int d, const int lane, const int j150,
           const _Float16* __restrict__ ldsH,
           float (&H1)[3][3], float (&H2)[3][3],
           float (&Vs)[3], float (&Vx)[3], _Float16 (&Rc)[3],
           const float oneE, float& S)
{
    const int half = (149 + d) >> 1;
    const int cvlo = half - (d < 149 ? d : 149);
    const int cvhi = half - (d > 149 ? d - 149 : 0);

    // LDS prefetch for diag d+8 (consumed 4 steps later; FIFO hides latency)
    _Float16 l[3];
    #pragma unroll
    for (int k = 0; k < 3; ++k)
        l[k] = ldsH[cellIdx(d + 8, j150 + 9600 * k)];

    // neighbor gather from H1 via DPP (unused k2 pieces DCE'd when !K2)
    float n0[3], n1[3], n2[3];
    if (SO) {   // odd: "right" uses h1[j-1], comps 0,1
        n0[0] = dppz<DPP_UP>(H1[0][0]);
        n1[0] = dppz<DPP_UP>(H1[0][1]);
        n0[1] = dppc<DPP_UP>(rl(H1[0][0], 63), H1[1][0]);
        n1[1] = dppc<DPP_UP>(rl(H1[0][1], 63), H1[1][1]);
        n0[2] = dppc<DPP_UP>(rl(H1[1][0], 63), H1[2][0]);
        n1[2] = dppc<DPP_UP>(rl(H1[1][1], 63), H1[2][1]);
        n2[0] = n2[1] = n2[2] = 0.0f;
    } else {    // even: "down" uses h1[j+1], comps 0,1,2
        n0[2] = dppz<DPP_DN>(H1[2][0]);
        n1[2] = dppz<DPP_DN>(H1[2][1]);
        n2[2] = dppz<DPP_DN>(H1[2][2]);
        n0[1] = dppc<DPP_DN>(rl(H1[2][0], 0), H1[1][0]);
        n1[1] = dppc<DPP_DN>(rl(H1[2][1], 0), H1[1][1]);
        n2[1] = dppc<DPP_DN>(rl(H1[2][2], 0), H1[1][2]);
        n0[0] = dppc<DPP_DN>(rl(H1[1][0], 0), H1[0][0]);
        n1[0] = dppc<DPP_DN>(rl(H1[1][1], 0), H1[0][1]);
        n2[0] = dppc<DPP_DN>(rl(H1[1][2], 0), H1[0][2]);
    }

    #pragma unroll
    for (int k = 0; k < 3; ++k) {
        if (k == 2 && !K2) continue;
        const int lo = cvlo - 64 * k, hi = cvhi - 64 * k;
        const bool cv = (lane >= lo) && (lane <= hi);
        const float sxl = cv ? Vs[k] : 0.0f;
        const float x2l = cv ? Vx[k] : 0.0f;

        float h0 = sxl * (((H2[k][0] + H2[k][1]) + H2[k][2]) + oneE);
        float h1, h2;
        if (SO) {
            h1 = fmaf(CGO, n0[k], CGE * n1[k]);
            h2 = fmaf(CGO, H1[k][0] + H1[k][1], CGE * H1[k][2]);
        } else {
            h1 = fmaf(CGO, H1[k][0], CGE * H1[k][1]);
            h2 = fmaf(CGO, n0[k] + n1[k], CGE * n2[k]);
        }
        if (k == 2) {   // slots >= 150 don't exist
            const bool pad = lane >= 22;
            h0 = pad ? 0.0f : h0;
            h1 = pad ? 0.0f : h1;
            h2 = pad ? 0.0f : h2;
        }
        S = fmaf(x2l, (h0 + h1) + h2, S);
        H2[k][0] = h0; H2[k][1] = h1; H2[k][2] = h2;
    }

    // FIFO: commit (cvt) diag d+4, insert new raw diag d+8 (always all 3 k,
    // so region B enters with a fully primed FIFO)
    Vs[0] = (float)Rc[0]; Vs[1] = (float)Rc[1]; Vs[2] = (float)Rc[2];
    Rc[0] = l[0]; Rc[1] = l[1]; Rc[2] = l[2];
}

__global__ __launch_bounds__(64)
void sw_fused(const float* __restrict__ x, float* __restrict__ part,
              float* __restrict__ out_atomic, int use_atomic) {
    const int b = blockIdx.x;
    const float* xb = x + (size_t)b * 22801;
    const int lane = threadIdx.x;
    const int j150 = 150 * lane;

    __shared__ _Float16 ldsH[22816];   // row-major exp2(x*log2e), f16

    // ---- phase A: coalesced load + exp into LDS ----
    for (int ii = 0; ii < 356; ++ii) {
        const int idx = ii * 64 + lane;
        ldsH[idx] = (_Float16)EXP2(xb[idx] * L2E);
    }
    if (lane < 17) {
        const int idx = 22784 + lane;
        ldsH[idx] = (_Float16)EXP2(xb[idx] * L2E);
    }
    __syncthreads();

    // ---- phase B: DP ----
    float Ha[3][3], Hb[3][3];
    #pragma unroll
    for (int k = 0; k < 3; ++k)
        #pragma unroll
        for (int c = 0; c < 3; ++c) { Ha[k][c] = 0.0f; Hb[k][c] = 0.0f; }

    float V0[3], V1[3], V2[3], V3[3];
    _Float16 R0[3], R1[3], R2[3], R3[3];
    #pragma unroll
    for (int k = 0; k < 3; ++k) {
        const int jk = j150 + 9600 * k;
        V0[k] = (float)ldsH[cellIdx(0, jk)];
        V1[k] = (float)ldsH[cellIdx(1, jk)];
        V2[k] = (float)ldsH[cellIdx(2, jk)];
        V3[k] = (float)ldsH[cellIdx(3, jk)];
        R0[k] = ldsH[cellIdx(4, jk)];
        R1[k] = ldsH[cellIdx(5, jk)];
        R2[k] = ldsH[cellIdx(6, jk)];
        R3[k] = ldsH[cellIdx(7, jk)];
    }

    float oneE = 1.0f;   // 2^-E
    float E = 0.0f;      // wave-uniform block-scale exponent
    float S = 0.0f;      // per-lane score sum, scaled by 2^-E

    // region A: d in [0,92), k2 block compiled out (first active at d=95)
    for (int d = 0; d < 92; d += 4) {
        stepF<0,false>(d + 0, lane, j150, ldsH, Hb, Ha, V0, V2, R0, oneE, S);
        stepF<1,false>(d + 1, lane, j150, ldsH, Ha, Hb, V1, V3, R1, oneE, S);
        stepF<0,false>(d + 2, lane, j150, ldsH, Hb, Ha, V2, V0, R2, oneE, S);
        stepF<1,false>(d + 3, lane, j150, ldsH, Ha, Hb, V3, V1, R3, oneE, S);
        float m = Hb[0][0];
        m = fmaxf(m, Hb[0][1]); m = fmaxf(m, Hb[0][2]);
        m = fmaxf(m, Hb[1][0]); m = fmaxf(m, Hb[1][1]); m = fmaxf(m, Hb[1][2]);
        const bool rn = __any(m > RTHR);
        const float sc = rn ? RSC : 1.0f;
        #pragma unroll
        for (int k = 0; k < 3; ++k)
            #pragma unroll
            for (int c = 0; c < 3; ++c) { Ha[k][c] *= sc; Hb[k][c] *= sc; }
        S *= sc; oneE *= sc; E += rn ? 64.0f : 0.0f;
    }
    // region B: d in [92,296), all k
    for (int d = 92; d < 296; d += 4) {
        stepF<0,true>(d + 0, lane, j150, ldsH, Hb, Ha, V0, V2, R0, oneE, S);
        stepF<1,true>(d + 1, lane, j150, ldsH, Ha, Hb, V1, V3, R1, oneE, S);
        stepF<0,true>(d + 2, lane, j150, ldsH, Hb, Ha, V2, V0, R2, oneE, S);
        stepF<1,true>(d + 3, lane, j150, ldsH, Ha, Hb, V3, V1, R3, oneE, S);
        float m = Hb[0][0];
        m = fmaxf(m, Hb[0][1]); m = fmaxf(m, Hb[0][2]);
        m = fmaxf(m, Hb[1][0]); m = fmaxf(m, Hb[1][1]); m = fmaxf(m, Hb[1][2]);
        m = fmaxf(m, Hb[2][0]); m = fmaxf(m, Hb[2][1]); m = fmaxf(m, Hb[2][2]);
        const bool rn = __any(m > RTHR);
        const float sc = rn ? RSC : 1.0f;
        #pragma unroll
        for (int k = 0; k < 3; ++k)
            #pragma unroll
            for (int c = 0; c < 3; ++c) { Ha[k][c] *= sc; Hb[k][c] *= sc; }
        S *= sc; oneE *= sc; E += rn ? 64.0f : 0.0f;
    }
    // tail: diags 296..298
    stepF<0,true>(296, lane, j150, ldsH, Hb, Ha, V0, V2, R0, oneE, S);
    stepF<1,true>(297, lane, j150, ldsH, Ha, Hb, V1, V3, R1, oneE, S);
    stepF<0,true>(298, lane, j150, ldsH, Hb, Ha, V2, V0, R2, oneE, S);

    // wave sum of S (E uniform across lanes)
    #pragma unroll
    for (int off = 32; off; off >>= 1) S += __shfl_xor(S, off, 64);
    if (lane == 0) {
        const float val = LN2 * (E + LOG2(S));
        if (use_atomic) atomicAdd(out_atomic, val);
        else            part[b] = val;
    }
}

__global__ __launch_bounds__(256)
void final_reduce(const float* __restrict__ part, float* __restrict__ out) {
    const int t = threadIdx.x;
    float v = part[t] + part[t + 256];
    #pragma unroll
    for (int off = 32; off; off >>= 1) v += __shfl_xor(v, off);
    __shared__ float ws[4];
    if ((t & 63) == 0) ws[t >> 6] = v;
    __syncthreads();
    if (t == 0) out[0] = ws[0] + ws[1] + ws[2] + ws[3];
}

extern "C" void kernel_launch(void* const* d_in, const int* in_sizes, int n_in,
                              void* d_out, int out_size, void* d_ws, size_t ws_size,
                              hipStream_t stream) {
    const float* x = (const float*)d_in[0];
    float* out = (float*)d_out;

    if (ws_size >= 512 * sizeof(float)) {
        float* part = (float*)d_ws;
        sw_fused<<<512, 64, 0, stream>>>(x, part, nullptr, 0);
        final_reduce<<<1, 256, 0, stream>>>(part, out);
    } else {
        hipMemsetAsync(out, 0, sizeof(float), stream);
        sw_fused<<<512, 64, 0, stream>>>(x, nullptr, out, 1);
    }
}